// Round 1
// baseline (1434.461 us; speedup 1.0000x reference)
//
#include <hip/hip_runtime.h>
#include <math.h>

#define HID 256
#define TD 32
#define NH 8
#define DH 32
#define NL 3
#define C1DIM 128
#define OUTDIM 2

// ---------- helpers ----------
__device__ __forceinline__ unsigned fkey(float f) {
  unsigned u = __float_as_uint(f);
  return (u & 0x80000000u) ? ~u : (u | 0x80000000u);
}
__device__ __forceinline__ float fdecode(unsigned k) {
  unsigned u = (k & 0x80000000u) ? (k & 0x7fffffffu) : ~k;
  return __uint_as_float(u);
}

// ---------- setup kernels ----------
__global__ void k_init(int* deg, unsigned* mm, int n) {
  int i = blockIdx.x * blockDim.x + threadIdx.x;
  if (i < n) deg[i] = 0;
  if (i == 0) { mm[0] = 0xFFFFFFFFu; mm[1] = 0u; }
}

__global__ void k_minmax(const float* __restrict__ ts, unsigned* mm, int n) {
  int i0 = blockIdx.x * blockDim.x + threadIdx.x;
  unsigned lmin = 0xFFFFFFFFu, lmax = 0u;
  for (int i = i0; i < n; i += gridDim.x * blockDim.x) {
    unsigned k = fkey(ts[i]);
    lmin = min(lmin, k); lmax = max(lmax, k);
  }
  atomicMin(&mm[0], lmin);
  atomicMax(&mm[1], lmax);
}

__global__ void k_time_enc(const float* __restrict__ ts, const float* __restrict__ freq,
                           const unsigned* __restrict__ mm, float* __restrict__ tf, int n) {
  int idx = blockIdx.x * blockDim.x + threadIdx.x;
  if (idx >= n * TD) return;
  int node = idx >> 5, j = idx & 31;
  float tmin = fdecode(mm[0]), tmax = fdecode(mm[1]);
  float t = (ts[node] - tmin) / (tmax - tmin + 1e-8f);
  float w = t * freq[j & 15];
  tf[idx] = (j < 16) ? cosf(w) : sinf(w);
}

__global__ void k_count(const int* __restrict__ dst, int* deg, int e) {
  int i = blockIdx.x * blockDim.x + threadIdx.x;
  if (i < e) atomicAdd(&deg[dst[i]], 1);
}

// single-block exclusive scan: deg[n] -> row_ptr[n+1]; also zeroes cursor[n]
__global__ __launch_bounds__(1024) void k_scan(const int* __restrict__ deg,
                                               int* __restrict__ row_ptr,
                                               int* __restrict__ cursor, int n) {
  __shared__ int sdata[1024];
  __shared__ int s_carry;
  int t = threadIdx.x;
  if (t == 0) s_carry = 0;
  __syncthreads();
  for (int base = 0; base < n; base += 1024) {
    int v = (base + t < n) ? deg[base + t] : 0;
    sdata[t] = v;
    __syncthreads();
    for (int off = 1; off < 1024; off <<= 1) {
      int x = (t >= off) ? sdata[t - off] : 0;
      __syncthreads();
      sdata[t] += x;
      __syncthreads();
    }
    int incl = sdata[t];
    int carry = s_carry;
    if (base + t < n) { row_ptr[base + t] = carry + incl - v; cursor[base + t] = 0; }
    __syncthreads();
    if (t == 1023) s_carry = carry + incl;
    __syncthreads();
  }
  if (t == 0) row_ptr[n] = s_carry;
}

__global__ void k_scatter(const int* __restrict__ src, const int* __restrict__ dst,
                          const int* __restrict__ row_ptr, int* cursor,
                          int* __restrict__ colbuf, int e) {
  int i = blockIdx.x * blockDim.x + threadIdx.x;
  if (i >= e) return;
  int d = dst[i];
  int p = atomicAdd(&cursor[d], 1);
  colbuf[row_ptr[d] + p] = src[i];
}

__global__ void k_concat(const float* __restrict__ h, const float* __restrict__ tf,
                         float* __restrict__ xt, int n) {
  int idx = blockIdx.x * blockDim.x + threadIdx.x;
  if (idx >= n * (HID + TD)) return;
  int node = idx / (HID + TD);
  int j = idx - node * (HID + TD);
  xt[idx] = (j < HID) ? h[node * HID + j] : tf[node * TD + (j - HID)];
}

// ---------- tiled fp32 GEMM: C[M,N] = A[M,K] @ B[K,N] + bias ; act: 0=none, 1=elu
__global__ __launch_bounds__(256) void k_gemm(const float* __restrict__ A,
                                              const float* __restrict__ B,
                                              const float* __restrict__ bias,
                                              float* __restrict__ C,
                                              int M, int Ncols, int Kdim, int act) {
  const int BM = 64, BN = 64, BK = 16;
  __shared__ float As[BK][BM + 4];
  __shared__ float Bs[BK][BN];
  int tid = threadIdx.x;
  int bx = blockIdx.x, by = blockIdx.y;
  int tx = tid & 15, ty = tid >> 4;
  int row0 = by * BM;
  int col0 = bx * BN;
  float acc[4][4] = {{0.f}};
  for (int k0 = 0; k0 < Kdim; k0 += BK) {
#pragma unroll
    for (int i = 0; i < 4; i++) {
      int idx = tid + i * 256;
      int r = idx >> 4, c = idx & 15;
      int gr = row0 + r;
      As[c][r] = (gr < M) ? A[(size_t)gr * Kdim + k0 + c] : 0.f;
    }
#pragma unroll
    for (int i = 0; i < 4; i++) {
      int idx = tid + i * 256;
      int r = idx >> 6, c = idx & 63;
      Bs[r][c] = B[(size_t)(k0 + r) * Ncols + col0 + c];
    }
    __syncthreads();
#pragma unroll
    for (int kk = 0; kk < BK; kk++) {
      float4 av = *reinterpret_cast<const float4*>(&As[kk][ty * 4]);
      float4 bv = *reinterpret_cast<const float4*>(&Bs[kk][tx * 4]);
      float a0[4] = {av.x, av.y, av.z, av.w};
      float b0[4] = {bv.x, bv.y, bv.z, bv.w};
#pragma unroll
      for (int i = 0; i < 4; i++)
#pragma unroll
        for (int j = 0; j < 4; j++) acc[i][j] += a0[i] * b0[j];
    }
    __syncthreads();
  }
#pragma unroll
  for (int i = 0; i < 4; i++) {
    int gr = row0 + ty * 4 + i;
    if (gr >= M) continue;
#pragma unroll
    for (int j = 0; j < 4; j++) {
      int gc = col0 + tx * 4 + j;
      float v = acc[i][j] + bias[gc];
      if (act == 1) v = (v > 0.f) ? v : expm1f(v);
      C[(size_t)gr * Ncols + gc] = v;
    }
  }
}

// ---------- fused per-node edge attention (online softmax) ----------
// block = 256 threads = 8 heads x 32 dims; one block per dst node
__global__ __launch_bounds__(256) void k_attn(const float* __restrict__ Q,
                                              const float* __restrict__ K,
                                              const float* __restrict__ V,
                                              const int* __restrict__ row_ptr,
                                              const int* __restrict__ colbuf,
                                              float* __restrict__ out, int n) {
  int node = blockIdx.x;
  int t = threadIdx.x;
  const float scale = 0.17677669529663687f;  // 1/sqrt(32)
  float q = Q[(size_t)node * HID + t];
  int beg = row_ptr[node], end = row_ptr[node + 1];
  float m = -INFINITY, s = 0.f, acc = 0.f;
  for (int i = beg; i < end; ++i) {
    int sn = colbuf[i];
    float kv = K[(size_t)sn * HID + t];
    float vv = V[(size_t)sn * HID + t];
    float p = q * kv;
    p += __shfl_xor(p, 1);
    p += __shfl_xor(p, 2);
    p += __shfl_xor(p, 4);
    p += __shfl_xor(p, 8);
    p += __shfl_xor(p, 16);
    float score = p * scale;
    float nm = fmaxf(m, score);
    float f = __expf(m - nm);     // m=-inf first iter -> f=0
    float ev = __expf(score - nm);
    s = s * f + ev;
    acc = acc * f + ev * vv;
    m = nm;
  }
  out[(size_t)node * HID + t] = (s > 0.f) ? (acc / s) : 0.f;
}

// ---------- pooling + classifier ----------
__global__ __launch_bounds__(256) void k_pool_partial(const float* __restrict__ h,
                                                      float* __restrict__ partial, int n) {
  int b = blockIdx.x, t = threadIdx.x;
  float s = 0.f;
  for (int r = b; r < n; r += 256) s += h[(size_t)r * HID + t];
  partial[b * HID + t] = s;
}

__global__ __launch_bounds__(256) void k_final(const float* __restrict__ partial,
                                               const float* __restrict__ c1W,
                                               const float* __restrict__ c1b,
                                               const float* __restrict__ c2W,
                                               const float* __restrict__ c2b,
                                               float* __restrict__ out, int n) {
  __shared__ float gl[HID];
  __shared__ float r1[C1DIM];
  int t = threadIdx.x;
  float s = 0.f;
  for (int b = 0; b < 256; b++) s += partial[b * HID + t];
  gl[t] = s / (float)n;
  __syncthreads();
  if (t < C1DIM) {
    float a = c1b[t];
    for (int k = 0; k < HID; k++) a += gl[k] * c1W[k * C1DIM + t];
    r1[t] = fmaxf(a, 0.f);
  }
  __syncthreads();
  if (t < OUTDIM) {
    float a = c2b[t];
    for (int k = 0; k < C1DIM; k++) a += r1[k] * c2W[k * OUTDIM + t];
    out[t] = a;
  }
}

// ---------- host launcher ----------
extern "C" void kernel_launch(void* const* d_in, const int* in_sizes, int n_in,
                              void* d_out, int out_size, void* d_ws, size_t ws_size,
                              hipStream_t stream) {
  const float* x    = (const float*)d_in[0];
  const float* ts   = (const float*)d_in[1];
  const int*   ei   = (const int*)d_in[2];
  const float* freq = (const float*)d_in[4];
  const float* inW  = (const float*)d_in[5];
  const float* inb  = (const float*)d_in[6];
  const float* qW   = (const float*)d_in[7];
  const float* qb   = (const float*)d_in[8];
  const float* kW   = (const float*)d_in[9];
  const float* kb   = (const float*)d_in[10];
  const float* vW   = (const float*)d_in[11];
  const float* vb   = (const float*)d_in[12];
  const float* oW   = (const float*)d_in[13];
  const float* ob   = (const float*)d_in[14];
  const float* c1W  = (const float*)d_in[15];
  const float* c1b  = (const float*)d_in[16];
  const float* c2W  = (const float*)d_in[17];
  const float* c2b  = (const float*)d_in[18];

  int n = in_sizes[1];
  int e = in_sizes[2] / 2;
  const int* src = ei;
  const int* dst = ei + e;

  // workspace carve-up (256B aligned)
  char* w = (char*)d_ws;
  size_t off = 0;
  auto alloc = [&](size_t bytes) -> char* {
    char* p = w + off;
    off = (off + bytes + 255) & ~(size_t)255;
    return p;
  };
  float*    tf      = (float*)alloc((size_t)n * TD * 4);
  float*    h       = (float*)alloc((size_t)n * HID * 4);
  float*    xt      = (float*)alloc((size_t)n * (HID + TD) * 4);
  float*    Qb      = (float*)alloc((size_t)n * HID * 4);
  float*    Kb      = (float*)alloc((size_t)n * HID * 4);
  float*    Vb      = (float*)alloc((size_t)n * HID * 4);
  float*    ao      = (float*)alloc((size_t)n * HID * 4);
  int*      deg     = (int*)alloc((size_t)n * 4);
  int*      cursor  = (int*)alloc((size_t)n * 4);
  int*      row_ptr = (int*)alloc((size_t)(n + 1) * 4);
  int*      colbuf  = (int*)alloc((size_t)e * 4);
  float*    partial = (float*)alloc((size_t)256 * HID * 4);
  unsigned* mm      = (unsigned*)alloc(256);

  int b256 = 256;
  // setup
  hipLaunchKernelGGL(k_init, dim3((n + 255) / 256), dim3(b256), 0, stream, deg, mm, n);
  hipLaunchKernelGGL(k_minmax, dim3(40), dim3(b256), 0, stream, ts, mm, n);
  hipLaunchKernelGGL(k_time_enc, dim3((n * TD + 255) / 256), dim3(b256), 0, stream, ts, freq, mm, tf, n);
  hipLaunchKernelGGL(k_count, dim3((e + 255) / 256), dim3(b256), 0, stream, dst, deg, e);
  hipLaunchKernelGGL(k_scan, dim3(1), dim3(1024), 0, stream, deg, row_ptr, cursor, n);
  hipLaunchKernelGGL(k_scatter, dim3((e + 255) / 256), dim3(b256), 0, stream, src, dst, row_ptr, cursor, colbuf, e);

  dim3 ggrid(HID / 64, (n + 63) / 64);
  // input projection: h = x @ inW + inb   (K=32)
  hipLaunchKernelGGL(k_gemm, ggrid, dim3(b256), 0, stream, x, inW, inb, h, n, HID, 32, 0);

  for (int l = 0; l < NL; ++l) {
    const float* qWl = qW + (size_t)l * (HID + TD) * HID;
    const float* kWl = kW + (size_t)l * (HID + TD) * HID;
    const float* vWl = vW + (size_t)l * HID * HID;
    const float* oWl = oW + (size_t)l * HID * HID;
    hipLaunchKernelGGL(k_concat, dim3((n * (HID + TD) + 255) / 256), dim3(b256), 0, stream, h, tf, xt, n);
    hipLaunchKernelGGL(k_gemm, ggrid, dim3(b256), 0, stream, xt, qWl, qb + l * HID, Qb, n, HID, HID + TD, 0);
    hipLaunchKernelGGL(k_gemm, ggrid, dim3(b256), 0, stream, xt, kWl, kb + l * HID, Kb, n, HID, HID + TD, 0);
    hipLaunchKernelGGL(k_gemm, ggrid, dim3(b256), 0, stream, h, vWl, vb + l * HID, Vb, n, HID, HID, 0);
    hipLaunchKernelGGL(k_attn, dim3(n), dim3(b256), 0, stream, Qb, Kb, Vb, row_ptr, colbuf, ao, n);
    hipLaunchKernelGGL(k_gemm, ggrid, dim3(b256), 0, stream, ao, oWl, ob + l * HID, h, n, HID, HID, 1);
  }

  hipLaunchKernelGGL(k_pool_partial, dim3(256), dim3(b256), 0, stream, h, partial, n);
  hipLaunchKernelGGL(k_final, dim3(1), dim3(b256), 0, stream, partial, c1W, c1b, c2W, c2b, (float*)d_out, n);
}

// Round 2
// 701.487 us; speedup vs baseline: 2.0449x; 2.0449x over previous
//
#include <hip/hip_runtime.h>
#include <math.h>

#define HID 256
#define TD 32
#define NL 3
#define C1DIM 128
#define OUTDIM 2

using half8  = __attribute__((ext_vector_type(8))) _Float16;
using half2v = __attribute__((ext_vector_type(2))) _Float16;
using f32x4  = __attribute__((ext_vector_type(4))) float;

typedef __attribute__((address_space(1))) void gbl_void_t;
typedef __attribute__((address_space(3))) void lds_void_t;

__device__ __forceinline__ void load16_to_lds(const void* g, void* l) {
  __builtin_amdgcn_global_load_lds((const gbl_void_t*)g, (lds_void_t*)l, 16, 0, 0);
}

// ---------- helpers ----------
__device__ __forceinline__ unsigned fkey(float f) {
  unsigned u = __float_as_uint(f);
  return (u & 0x80000000u) ? ~u : (u | 0x80000000u);
}
__device__ __forceinline__ float fdecode(unsigned k) {
  unsigned u = (k & 0x80000000u) ? (k & 0x7fffffffu) : ~k;
  return __uint_as_float(u);
}

// ---------- setup kernels ----------
__global__ void k_init(int* deg, unsigned* mm, int n) {
  int i = blockIdx.x * blockDim.x + threadIdx.x;
  if (i < n) deg[i] = 0;
  if (i == 0) { mm[0] = 0xFFFFFFFFu; mm[1] = 0u; }
}

__global__ void k_minmax(const float* __restrict__ ts, unsigned* mm, int n) {
  int i0 = blockIdx.x * blockDim.x + threadIdx.x;
  unsigned lmin = 0xFFFFFFFFu, lmax = 0u;
  for (int i = i0; i < n; i += gridDim.x * blockDim.x) {
    unsigned k = fkey(ts[i]);
    lmin = min(lmin, k); lmax = max(lmax, k);
  }
  atomicMin(&mm[0], lmin);
  atomicMax(&mm[1], lmax);
}

// time encoding -> fp16 [N][32]
__global__ void k_time_enc(const float* __restrict__ ts, const float* __restrict__ freq,
                           const unsigned* __restrict__ mm, _Float16* __restrict__ tfh, int n) {
  int idx = blockIdx.x * blockDim.x + threadIdx.x;
  if (idx >= n * TD) return;
  int node = idx >> 5, j = idx & 31;
  float tmin = fdecode(mm[0]), tmax = fdecode(mm[1]);
  float t = (ts[node] - tmin) / (tmax - tmin + 1e-8f);
  float w = t * freq[j & 15];
  tfh[idx] = (_Float16)((j < 16) ? cosf(w) : sinf(w));
}

__global__ void k_cvt(const float* __restrict__ in, _Float16* __restrict__ out, int total) {
  int i = blockIdx.x * blockDim.x + threadIdx.x;
  if (i < total) out[i] = (_Float16)in[i];
}

// W[L][K][N] fp32 -> Wt[L][N][K] fp16 (output-indexed: coalesced writes)
__global__ void k_wt(const float* __restrict__ W, _Float16* __restrict__ Wt,
                     int K, int N, int total) {
  int idx = blockIdx.x * blockDim.x + threadIdx.x;
  if (idx >= total) return;
  int mat = idx / (K * N);
  int rem = idx - mat * (K * N);
  int nrow = rem / K;
  int k = rem - nrow * K;
  Wt[idx] = (_Float16)W[(size_t)mat * K * N + (size_t)k * N + nrow];
}

__global__ void k_count(const int* __restrict__ dst, int* deg, int e) {
  int i = blockIdx.x * blockDim.x + threadIdx.x;
  if (i < e) atomicAdd(&deg[dst[i]], 1);
}

// single-block scan via wave shuffles: deg[n] -> row_ptr[n+1]; zero cursor
__global__ __launch_bounds__(1024) void k_scan(const int* __restrict__ deg,
                                               int* __restrict__ row_ptr,
                                               int* __restrict__ cursor, int n) {
  __shared__ int wsum[16];
  __shared__ int s_carry;
  int t = threadIdx.x;
  int lane = t & 63, wid = t >> 6;
  if (t == 0) s_carry = 0;
  __syncthreads();
  for (int base = 0; base < n; base += 1024) {
    int idx = base + t;
    int v = (idx < n) ? deg[idx] : 0;
    int x = v;
#pragma unroll
    for (int off = 1; off < 64; off <<= 1) {
      int y = __shfl_up(x, off);
      if (lane >= off) x += y;
    }
    if (lane == 63) wsum[wid] = x;
    __syncthreads();
    if (wid == 0) {
      int w = (lane < 16) ? wsum[lane] : 0;
#pragma unroll
      for (int off = 1; off < 16; off <<= 1) {
        int y = __shfl_up(w, off);
        if (lane >= off) w += y;
      }
      if (lane < 16) wsum[lane] = w;
    }
    __syncthreads();
    int wprev = (wid > 0) ? wsum[wid - 1] : 0;
    int incl = x + wprev;
    int carry = s_carry;
    if (idx < n) { row_ptr[idx] = carry + incl - v; cursor[idx] = 0; }
    __syncthreads();
    if (t == 1023) s_carry = carry + incl;
    __syncthreads();
  }
  if (t == 0) row_ptr[n] = s_carry;
}

__global__ void k_scatter(const int* __restrict__ src, const int* __restrict__ dst,
                          const int* __restrict__ row_ptr, int* cursor,
                          int* __restrict__ colbuf, int e) {
  int i = blockIdx.x * blockDim.x + threadIdx.x;
  if (i >= e) return;
  int d = dst[i];
  int p = atomicAdd(&cursor[d], 1);
  colbuf[row_ptr[d] + p] = src[i];
}

// ---------- fp16 MFMA GEMM ----------
// C[M,N](fp16) = concat(A1[M,K1], A2[M,K2])[M,Ktot] @ Bt^T + bias ; act 1 = ELU
// Bt is [N][Ktot] fp16 (pre-transposed weights). Tile 128x64, BK=32, 4 waves.
// LDS A layout: slot = kg*128 + row (16B = 8 fp16 of k-range kg*8..kg*8+8)
// LDS B layout: slot = kg*64 + col
__global__ __launch_bounds__(256) void k_gemm_f16(
    const _Float16* __restrict__ A1, int K1,
    const _Float16* __restrict__ A2, int K2,
    const _Float16* __restrict__ Bt,
    const float* __restrict__ bias,
    _Float16* __restrict__ C,
    int M, int Ncols, int Ktot, int act) {
  __shared__ half8 smem8[2 * 768];  // 2 bufs x (8KB A + 4KB B)
  char* smem = (char*)smem8;
  const int tid = threadIdx.x;
  const int lane = tid & 63, wave = tid >> 6;
  const int wm = wave >> 1, wn = wave & 1;
  const int row0 = blockIdx.y * 128;
  const int col0 = blockIdx.x * 64;

  auto stage = [&](int buf, int k0) {
    char* sA = smem + buf * 12288;
    char* sB = sA + 8192;
#pragma unroll
    for (int i = 0; i < 2; ++i) {
      int kg = i * 2 + (wave >> 1);
      int row = (wave & 1) * 64 + lane;
      int grow = row0 + row; if (grow > M - 1) grow = M - 1;
      int k = k0 + kg * 8;
      const _Float16* src = (k < K1) ? (A1 + (size_t)grow * K1 + k)
                                     : (A2 + (size_t)grow * K2 + (k - K1));
      load16_to_lds(src, sA + (i * 256 + wave * 64) * 16);
    }
    {
      const _Float16* src = Bt + (size_t)(col0 + lane) * Ktot + k0 + wave * 8;
      load16_to_lds(src, sB + wave * 64 * 16);
    }
  };

  f32x4 acc[4][2];
#pragma unroll
  for (int mf = 0; mf < 4; ++mf)
#pragma unroll
    for (int nf = 0; nf < 2; ++nf) acc[mf][nf] = f32x4{0.f, 0.f, 0.f, 0.f};

  const int nsteps = Ktot >> 5;
  int cur = 0;
  stage(0, 0);
  __syncthreads();
  for (int st = 0; st < nsteps; ++st) {
    if (st + 1 < nsteps) stage(cur ^ 1, (st + 1) * 32);
    char* sA = smem + cur * 12288;
    char* sB = sA + 8192;
    half8 af[4], bf[2];
#pragma unroll
    for (int mf = 0; mf < 4; ++mf) {
      int slot = (lane >> 4) * 128 + wm * 64 + mf * 16 + (lane & 15);
      af[mf] = *(const half8*)(sA + slot * 16);
    }
#pragma unroll
    for (int nf = 0; nf < 2; ++nf) {
      int slot = (lane >> 4) * 64 + wn * 32 + nf * 16 + (lane & 15);
      bf[nf] = *(const half8*)(sB + slot * 16);
    }
#pragma unroll
    for (int mf = 0; mf < 4; ++mf)
#pragma unroll
      for (int nf = 0; nf < 2; ++nf)
        acc[mf][nf] = __builtin_amdgcn_mfma_f32_16x16x32_f16(af[mf], bf[nf], acc[mf][nf], 0, 0, 0);
    __syncthreads();
    cur ^= 1;
  }

  // epilogue: C/D layout col=lane&15, row=(lane>>4)*4+r
  const int rbase = row0 + wm * 64 + (lane >> 4) * 4;
  const int cbase = col0 + wn * 32 + (lane & 15);
#pragma unroll
  for (int nf = 0; nf < 2; ++nf) {
    int col = cbase + nf * 16;
    float bv = bias[col];
#pragma unroll
    for (int mf = 0; mf < 4; ++mf) {
#pragma unroll
      for (int r = 0; r < 4; ++r) {
        int row = rbase + mf * 16 + r;
        if (row < M) {
          float v = acc[mf][nf][r] + bv;
          if (act == 1) v = (v > 0.f) ? v : expm1f(v);
          C[(size_t)row * Ncols + col] = (_Float16)v;
        }
      }
    }
  }
}

// ---------- fused per-node edge attention (fp16, 2 nodes/block, unroll 2) ----------
__global__ __launch_bounds__(256) void k_attn(const _Float16* __restrict__ Q,
                                              const _Float16* __restrict__ K,
                                              const _Float16* __restrict__ V,
                                              const int* __restrict__ row_ptr,
                                              const int* __restrict__ colbuf,
                                              _Float16* __restrict__ out, int n) {
  int node = blockIdx.x * 2 + (threadIdx.x >> 7);
  if (node >= n) return;
  int lt = threadIdx.x & 127;
  int d = lt * 2;
  const float scale = 0.17677669529663687f;  // 1/sqrt(32)
  half2v qh = *(const half2v*)(Q + (size_t)node * HID + d);
  float q0 = (float)qh.x * scale, q1 = (float)qh.y * scale;
  int beg = row_ptr[node], end = row_ptr[node + 1];
  float m = -INFINITY, s = 0.f, a0 = 0.f, a1 = 0.f;
  int i = beg;
  for (; i + 2 <= end; i += 2) {
    int s0 = colbuf[i], s1 = colbuf[i + 1];
    half2v k0 = *(const half2v*)(K + (size_t)s0 * HID + d);
    half2v v0 = *(const half2v*)(V + (size_t)s0 * HID + d);
    half2v k1 = *(const half2v*)(K + (size_t)s1 * HID + d);
    half2v v1 = *(const half2v*)(V + (size_t)s1 * HID + d);
    float p0 = q0 * (float)k0.x + q1 * (float)k0.y;
    float p1 = q0 * (float)k1.x + q1 * (float)k1.y;
    p0 += __shfl_xor(p0, 1);  p1 += __shfl_xor(p1, 1);
    p0 += __shfl_xor(p0, 2);  p1 += __shfl_xor(p1, 2);
    p0 += __shfl_xor(p0, 4);  p1 += __shfl_xor(p1, 4);
    p0 += __shfl_xor(p0, 8);  p1 += __shfl_xor(p1, 8);
    {
      float nm = fmaxf(m, p0); float f = __expf(m - nm); float e = __expf(p0 - nm);
      s = s * f + e; a0 = a0 * f + e * (float)v0.x; a1 = a1 * f + e * (float)v0.y; m = nm;
    }
    {
      float nm = fmaxf(m, p1); float f = __expf(m - nm); float e = __expf(p1 - nm);
      s = s * f + e; a0 = a0 * f + e * (float)v1.x; a1 = a1 * f + e * (float)v1.y; m = nm;
    }
  }
  if (i < end) {
    int s0 = colbuf[i];
    half2v k0 = *(const half2v*)(K + (size_t)s0 * HID + d);
    half2v v0 = *(const half2v*)(V + (size_t)s0 * HID + d);
    float p0 = q0 * (float)k0.x + q1 * (float)k0.y;
    p0 += __shfl_xor(p0, 1);
    p0 += __shfl_xor(p0, 2);
    p0 += __shfl_xor(p0, 4);
    p0 += __shfl_xor(p0, 8);
    float nm = fmaxf(m, p0); float f = __expf(m - nm); float e = __expf(p0 - nm);
    s = s * f + e; a0 = a0 * f + e * (float)v0.x; a1 = a1 * f + e * (float)v0.y; m = nm;
  }
  half2v o;
  if (s > 0.f) { o.x = (_Float16)(a0 / s); o.y = (_Float16)(a1 / s); }
  else         { o.x = (_Float16)0.f; o.y = (_Float16)0.f; }
  *(half2v*)(out + (size_t)node * HID + d) = o;
}

// ---------- pooling + classifier (fp32 weights for precision) ----------
__global__ __launch_bounds__(256) void k_pool_partial(const _Float16* __restrict__ h,
                                                      float* __restrict__ partial, int n) {
  int b = blockIdx.x, t = threadIdx.x;
  float s = 0.f;
  for (int r = b; r < n; r += 256) s += (float)h[(size_t)r * HID + t];
  partial[b * HID + t] = s;
}

__global__ __launch_bounds__(256) void k_final(const float* __restrict__ partial,
                                               const float* __restrict__ c1W,
                                               const float* __restrict__ c1b,
                                               const float* __restrict__ c2W,
                                               const float* __restrict__ c2b,
                                               float* __restrict__ out, int n) {
  __shared__ float gl[HID];
  __shared__ float r1[C1DIM];
  int t = threadIdx.x;
  float s = 0.f;
  for (int b = 0; b < 256; b++) s += partial[b * HID + t];
  gl[t] = s / (float)n;
  __syncthreads();
  if (t < C1DIM) {
    float a = c1b[t];
    for (int k = 0; k < HID; k++) a += gl[k] * c1W[k * C1DIM + t];
    r1[t] = fmaxf(a, 0.f);
  }
  __syncthreads();
  if (t < OUTDIM) {
    float a = c2b[t];
    for (int k = 0; k < C1DIM; k++) a += r1[k] * c2W[k * OUTDIM + t];
    out[t] = a;
  }
}

// ---------- host launcher ----------
extern "C" void kernel_launch(void* const* d_in, const int* in_sizes, int n_in,
                              void* d_out, int out_size, void* d_ws, size_t ws_size,
                              hipStream_t stream) {
  const float* x    = (const float*)d_in[0];
  const float* ts   = (const float*)d_in[1];
  const int*   ei   = (const int*)d_in[2];
  const float* freq = (const float*)d_in[4];
  const float* inW  = (const float*)d_in[5];
  const float* inb  = (const float*)d_in[6];
  const float* qW   = (const float*)d_in[7];
  const float* qb   = (const float*)d_in[8];
  const float* kW   = (const float*)d_in[9];
  const float* kb   = (const float*)d_in[10];
  const float* vW   = (const float*)d_in[11];
  const float* vb   = (const float*)d_in[12];
  const float* oW   = (const float*)d_in[13];
  const float* ob   = (const float*)d_in[14];
  const float* c1W  = (const float*)d_in[15];
  const float* c1b  = (const float*)d_in[16];
  const float* c2W  = (const float*)d_in[17];
  const float* c2b  = (const float*)d_in[18];

  int n = in_sizes[1];
  int e = in_sizes[2] / 2;
  const int* src = ei;
  const int* dst = ei + e;

  char* w = (char*)d_ws;
  size_t off = 0;
  auto alloc = [&](size_t bytes) -> char* {
    char* p = w + off;
    off = (off + bytes + 255) & ~(size_t)255;
    return p;
  };
  _Float16* tfh     = (_Float16*)alloc((size_t)n * TD * 2);
  _Float16* xh      = (_Float16*)alloc((size_t)n * 32 * 2);
  _Float16* h       = (_Float16*)alloc((size_t)n * HID * 2);
  _Float16* Qh      = (_Float16*)alloc((size_t)n * HID * 2);
  _Float16* Kh      = (_Float16*)alloc((size_t)n * HID * 2);
  _Float16* Vh      = (_Float16*)alloc((size_t)n * HID * 2);
  _Float16* ao      = (_Float16*)alloc((size_t)n * HID * 2);
  _Float16* inWt    = (_Float16*)alloc((size_t)32 * HID * 2);
  _Float16* qWt     = (_Float16*)alloc((size_t)NL * (HID + TD) * HID * 2);
  _Float16* kWt     = (_Float16*)alloc((size_t)NL * (HID + TD) * HID * 2);
  _Float16* vWt     = (_Float16*)alloc((size_t)NL * HID * HID * 2);
  _Float16* oWt     = (_Float16*)alloc((size_t)NL * HID * HID * 2);
  int*      deg     = (int*)alloc((size_t)n * 4);
  int*      cursor  = (int*)alloc((size_t)n * 4);
  int*      row_ptr = (int*)alloc((size_t)(n + 1) * 4);
  int*      colbuf  = (int*)alloc((size_t)e * 4);
  float*    partial = (float*)alloc((size_t)256 * HID * 4);
  unsigned* mm      = (unsigned*)alloc(256);

  int b256 = 256;
  hipLaunchKernelGGL(k_init, dim3((n + 255) / 256), dim3(b256), 0, stream, deg, mm, n);
  hipLaunchKernelGGL(k_minmax, dim3(40), dim3(b256), 0, stream, ts, mm, n);
  hipLaunchKernelGGL(k_time_enc, dim3((n * TD + 255) / 256), dim3(b256), 0, stream, ts, freq, mm, tfh, n);
  hipLaunchKernelGGL(k_cvt, dim3((n * 32 + 255) / 256), dim3(b256), 0, stream, x, xh, n * 32);
  // weight transpose+convert
  hipLaunchKernelGGL(k_wt, dim3((32 * HID + 255) / 256), dim3(b256), 0, stream, inW, inWt, 32, HID, 32 * HID);
  {
    int tq = NL * (HID + TD) * HID;
    hipLaunchKernelGGL(k_wt, dim3((tq + 255) / 256), dim3(b256), 0, stream, qW, qWt, HID + TD, HID, tq);
    hipLaunchKernelGGL(k_wt, dim3((tq + 255) / 256), dim3(b256), 0, stream, kW, kWt, HID + TD, HID, tq);
    int tv = NL * HID * HID;
    hipLaunchKernelGGL(k_wt, dim3((tv + 255) / 256), dim3(b256), 0, stream, vW, vWt, HID, HID, tv);
    hipLaunchKernelGGL(k_wt, dim3((tv + 255) / 256), dim3(b256), 0, stream, oW, oWt, HID, HID, tv);
  }
  hipLaunchKernelGGL(k_count, dim3((e + 255) / 256), dim3(b256), 0, stream, dst, deg, e);
  hipLaunchKernelGGL(k_scan, dim3(1), dim3(1024), 0, stream, deg, row_ptr, cursor, n);
  hipLaunchKernelGGL(k_scatter, dim3((e + 255) / 256), dim3(b256), 0, stream, src, dst, row_ptr, cursor, colbuf, e);

  dim3 ggrid(HID / 64, (n + 127) / 128);
  // input projection: h = x @ inW + inb (K=32)
  hipLaunchKernelGGL(k_gemm_f16, ggrid, dim3(b256), 0, stream,
                     xh, 32, xh, 32, inWt, inb, h, n, HID, 32, 0);

  for (int l = 0; l < NL; ++l) {
    const _Float16* qWtl = qWt + (size_t)l * (HID + TD) * HID;
    const _Float16* kWtl = kWt + (size_t)l * (HID + TD) * HID;
    const _Float16* vWtl = vWt + (size_t)l * HID * HID;
    const _Float16* oWtl = oWt + (size_t)l * HID * HID;
    hipLaunchKernelGGL(k_gemm_f16, ggrid, dim3(b256), 0, stream,
                       h, HID, tfh, TD, qWtl, qb + l * HID, Qh, n, HID, HID + TD, 0);
    hipLaunchKernelGGL(k_gemm_f16, ggrid, dim3(b256), 0, stream,
                       h, HID, tfh, TD, kWtl, kb + l * HID, Kh, n, HID, HID + TD, 0);
    hipLaunchKernelGGL(k_gemm_f16, ggrid, dim3(b256), 0, stream,
                       h, HID, h, HID, vWtl, vb + l * HID, Vh, n, HID, HID, 0);
    hipLaunchKernelGGL(k_attn, dim3((n + 1) / 2), dim3(b256), 0, stream,
                       Qh, Kh, Vh, row_ptr, colbuf, ao, n);
    hipLaunchKernelGGL(k_gemm_f16, ggrid, dim3(b256), 0, stream,
                       ao, HID, ao, HID, oWtl, ob + l * HID, h, n, HID, HID, 1);
  }

  hipLaunchKernelGGL(k_pool_partial, dim3(256), dim3(b256), 0, stream, h, partial, n);
  hipLaunchKernelGGL(k_final, dim3(1), dim3(b256), 0, stream, partial, c1W, c1b, c2W, c2b, (float*)d_out, n);
}

// Round 3
// 615.339 us; speedup vs baseline: 2.3312x; 1.1400x over previous
//
#include <hip/hip_runtime.h>
#include <math.h>

#define HID 256
#define TD 32
#define NL 3
#define C1DIM 128
#define OUTDIM 2
#define QKVW 768

using half8  = __attribute__((ext_vector_type(8))) _Float16;
using half2v = __attribute__((ext_vector_type(2))) _Float16;
using f32x4  = __attribute__((ext_vector_type(4))) float;

typedef __attribute__((address_space(1))) void gbl_void_t;
typedef __attribute__((address_space(3))) void lds_void_t;

__device__ __forceinline__ void load16_to_lds(const void* g, void* l) {
  __builtin_amdgcn_global_load_lds((const gbl_void_t*)g, (lds_void_t*)l, 16, 0, 0);
}

__device__ __forceinline__ float dot8(half8 a, half8 b) {
#if __has_builtin(__builtin_amdgcn_fdot2)
  union { half8 v; half2v h2[4]; } ua, ub;
  ua.v = a; ub.v = b;
  float acc = 0.f;
#pragma unroll
  for (int j = 0; j < 4; ++j) acc = __builtin_amdgcn_fdot2(ua.h2[j], ub.h2[j], acc, false);
  return acc;
#else
  float acc = 0.f;
#pragma unroll
  for (int j = 0; j < 8; ++j) acc += (float)a[j] * (float)b[j];
  return acc;
#endif
}

// ---------- helpers ----------
__device__ __forceinline__ unsigned fkey(float f) {
  unsigned u = __float_as_uint(f);
  return (u & 0x80000000u) ? ~u : (u | 0x80000000u);
}
__device__ __forceinline__ float fdecode(unsigned k) {
  unsigned u = (k & 0x80000000u) ? (k & 0x7fffffffu) : ~k;
  return __uint_as_float(u);
}

// ---------- setup kernels ----------
__global__ void k_init(int* deg, unsigned* mm, int n) {
  int i = blockIdx.x * blockDim.x + threadIdx.x;
  if (i < n) deg[i] = 0;
  if (i == 0) { mm[0] = 0xFFFFFFFFu; mm[1] = 0u; }
}

__global__ void k_minmax(const float* __restrict__ ts, unsigned* mm, int n) {
  int i0 = blockIdx.x * blockDim.x + threadIdx.x;
  unsigned lmin = 0xFFFFFFFFu, lmax = 0u;
  for (int i = i0; i < n; i += gridDim.x * blockDim.x) {
    unsigned k = fkey(ts[i]);
    lmin = min(lmin, k); lmax = max(lmax, k);
  }
  atomicMin(&mm[0], lmin);
  atomicMax(&mm[1], lmax);
}

__global__ void k_time_enc(const float* __restrict__ ts, const float* __restrict__ freq,
                           const unsigned* __restrict__ mm, _Float16* __restrict__ tfh, int n) {
  int idx = blockIdx.x * blockDim.x + threadIdx.x;
  if (idx >= n * TD) return;
  int node = idx >> 5, j = idx & 31;
  float tmin = fdecode(mm[0]), tmax = fdecode(mm[1]);
  float t = (ts[node] - tmin) / (tmax - tmin + 1e-8f);
  float w = t * freq[j & 15];
  tfh[idx] = (_Float16)((j < 16) ? cosf(w) : sinf(w));
}

__global__ void k_cvt(const float* __restrict__ in, _Float16* __restrict__ out, int total) {
  int i = blockIdx.x * blockDim.x + threadIdx.x;
  if (i < total) out[i] = (_Float16)in[i];
}

// W[K][N] fp32 -> Wt[N][K] fp16 (for input proj / O proj, per-matrix)
__global__ void k_wt(const float* __restrict__ W, _Float16* __restrict__ Wt,
                     int K, int N, int total) {
  int idx = blockIdx.x * blockDim.x + threadIdx.x;
  if (idx >= total) return;
  int mat = idx / (K * N);
  int rem = idx - mat * (K * N);
  int nrow = rem / K;
  int k = rem - nrow * K;
  Wt[idx] = (_Float16)W[(size_t)mat * K * N + (size_t)k * N + nrow];
}

// fused QKV weight: out[L][768][288]; rows 0..255=qW^T, 256..511=kW^T, 512..767=vW^T zero-padded K
__global__ void k_wt_qkv(const float* __restrict__ qW, const float* __restrict__ kW,
                         const float* __restrict__ vW, _Float16* __restrict__ Wt, int total) {
  int idx = blockIdx.x * blockDim.x + threadIdx.x;
  if (idx >= total) return;
  const int KQ = HID + TD;  // 288
  int l = idx / (QKVW * KQ);
  int rem = idx - l * (QKVW * KQ);
  int nrow = rem / KQ;
  int k = rem - nrow * KQ;
  float v;
  if (nrow < 256)      v = qW[(size_t)l * KQ * HID + (size_t)k * HID + nrow];
  else if (nrow < 512) v = kW[(size_t)l * KQ * HID + (size_t)k * HID + (nrow - 256)];
  else                 v = (k < HID) ? vW[(size_t)l * HID * HID + (size_t)k * HID + (nrow - 512)] : 0.f;
  Wt[idx] = (_Float16)v;
}

__global__ void k_fuse_bias(const float* __restrict__ qb, const float* __restrict__ kb,
                            const float* __restrict__ vb, float* __restrict__ out, int total) {
  int idx = blockIdx.x * blockDim.x + threadIdx.x;
  if (idx >= total) return;
  int l = idx / QKVW;
  int j = idx - l * QKVW;
  float v;
  if (j < 256)      v = qb[l * HID + j];
  else if (j < 512) v = kb[l * HID + (j - 256)];
  else              v = vb[l * HID + (j - 512)];
  out[idx] = v;
}

__global__ void k_count(const int* __restrict__ dst, int* deg, int e) {
  int i = blockIdx.x * blockDim.x + threadIdx.x;
  if (i < e) atomicAdd(&deg[dst[i]], 1);
}

__global__ __launch_bounds__(1024) void k_scan(const int* __restrict__ deg,
                                               int* __restrict__ row_ptr,
                                               int* __restrict__ cursor, int n) {
  __shared__ int wsum[16];
  __shared__ int s_carry;
  int t = threadIdx.x;
  int lane = t & 63, wid = t >> 6;
  if (t == 0) s_carry = 0;
  __syncthreads();
  for (int base = 0; base < n; base += 1024) {
    int idx = base + t;
    int v = (idx < n) ? deg[idx] : 0;
    int x = v;
#pragma unroll
    for (int off = 1; off < 64; off <<= 1) {
      int y = __shfl_up(x, off);
      if (lane >= off) x += y;
    }
    if (lane == 63) wsum[wid] = x;
    __syncthreads();
    if (wid == 0) {
      int w = (lane < 16) ? wsum[lane] : 0;
#pragma unroll
      for (int off = 1; off < 16; off <<= 1) {
        int y = __shfl_up(w, off);
        if (lane >= off) w += y;
      }
      if (lane < 16) wsum[lane] = w;
    }
    __syncthreads();
    int wprev = (wid > 0) ? wsum[wid - 1] : 0;
    int incl = x + wprev;
    int carry = s_carry;
    if (idx < n) { row_ptr[idx] = carry + incl - v; cursor[idx] = 0; }
    __syncthreads();
    if (t == 1023) s_carry = carry + incl;
    __syncthreads();
  }
  if (t == 0) row_ptr[n] = s_carry;
}

__global__ void k_scatter(const int* __restrict__ src, const int* __restrict__ dst,
                          const int* __restrict__ row_ptr, int* cursor,
                          int* __restrict__ colbuf, int e) {
  int i = blockIdx.x * blockDim.x + threadIdx.x;
  if (i >= e) return;
  int d = dst[i];
  int p = atomicAdd(&cursor[d], 1);
  colbuf[row_ptr[d] + p] = src[i];
}

// ---------- fp16 MFMA GEMM ----------
// C[M,Ncols](fp16) = concat(A1[M,K1], A2[M,K2]) @ Bt^T + bias ; act 1 = ELU
__global__ __launch_bounds__(256) void k_gemm_f16(
    const _Float16* __restrict__ A1, int K1,
    const _Float16* __restrict__ A2, int K2,
    const _Float16* __restrict__ Bt,
    const float* __restrict__ bias,
    _Float16* __restrict__ C,
    int M, int Ncols, int Ktot, int act) {
  __shared__ half8 smem8[2 * 768];
  char* smem = (char*)smem8;
  const int tid = threadIdx.x;
  const int lane = tid & 63, wave = tid >> 6;
  const int wm = wave >> 1, wn = wave & 1;
  const int row0 = blockIdx.y * 128;
  const int col0 = blockIdx.x * 64;

  auto stage = [&](int buf, int k0) {
    char* sA = smem + buf * 12288;
    char* sB = sA + 8192;
#pragma unroll
    for (int i = 0; i < 2; ++i) {
      int kg = i * 2 + (wave >> 1);
      int row = (wave & 1) * 64 + lane;
      int grow = row0 + row; if (grow > M - 1) grow = M - 1;
      int k = k0 + kg * 8;
      const _Float16* src = (k < K1) ? (A1 + (size_t)grow * K1 + k)
                                     : (A2 + (size_t)grow * K2 + (k - K1));
      load16_to_lds(src, sA + (i * 256 + wave * 64) * 16);
    }
    {
      const _Float16* src = Bt + (size_t)(col0 + lane) * Ktot + k0 + wave * 8;
      load16_to_lds(src, sB + wave * 64 * 16);
    }
  };

  f32x4 acc[4][2];
#pragma unroll
  for (int mf = 0; mf < 4; ++mf)
#pragma unroll
    for (int nf = 0; nf < 2; ++nf) acc[mf][nf] = f32x4{0.f, 0.f, 0.f, 0.f};

  const int nsteps = Ktot >> 5;
  int cur = 0;
  stage(0, 0);
  __syncthreads();
  for (int st = 0; st < nsteps; ++st) {
    if (st + 1 < nsteps) stage(cur ^ 1, (st + 1) * 32);
    char* sA = smem + cur * 12288;
    char* sB = sA + 8192;
    half8 af[4], bf[2];
#pragma unroll
    for (int mf = 0; mf < 4; ++mf) {
      int slot = (lane >> 4) * 128 + wm * 64 + mf * 16 + (lane & 15);
      af[mf] = *(const half8*)(sA + slot * 16);
    }
#pragma unroll
    for (int nf = 0; nf < 2; ++nf) {
      int slot = (lane >> 4) * 64 + wn * 32 + nf * 16 + (lane & 15);
      bf[nf] = *(const half8*)(sB + slot * 16);
    }
#pragma unroll
    for (int mf = 0; mf < 4; ++mf)
#pragma unroll
      for (int nf = 0; nf < 2; ++nf)
        acc[mf][nf] = __builtin_amdgcn_mfma_f32_16x16x32_f16(af[mf], bf[nf], acc[mf][nf], 0, 0, 0);
    __syncthreads();
    cur ^= 1;
  }

  const int rbase = row0 + wm * 64 + (lane >> 4) * 4;
  const int cbase = col0 + wn * 32 + (lane & 15);
#pragma unroll
  for (int nf = 0; nf < 2; ++nf) {
    int col = cbase + nf * 16;
    float bv = bias[col];
#pragma unroll
    for (int mf = 0; mf < 4; ++mf) {
#pragma unroll
      for (int r = 0; r < 4; ++r) {
        int row = rbase + mf * 16 + r;
        if (row < M) {
          float v = acc[mf][nf][r] + bv;
          if (act == 1) v = (v > 0.f) ? v : expm1f(v);
          C[(size_t)row * Ncols + col] = (_Float16)v;
        }
      }
    }
  }
}

// ---------- fused per-node edge attention ----------
// QKV[n][768]: Q|K|V. 32 threads/node (8 dims each), 8 nodes/block.
__global__ __launch_bounds__(256) void k_attn(const _Float16* __restrict__ QKV,
                                              const int* __restrict__ row_ptr,
                                              const int* __restrict__ colbuf,
                                              _Float16* __restrict__ out, int n) {
  int node = blockIdx.x * 8 + (threadIdx.x >> 5);
  if (node >= n) return;
  int t32 = threadIdx.x & 31;
  int d = t32 * 8;
  const float scale = 0.17677669529663687f;  // 1/sqrt(32)
  half8 qh = *(const half8*)(QKV + (size_t)node * QKVW + d);
#pragma unroll
  for (int j = 0; j < 8; ++j) qh[j] = (_Float16)((float)qh[j] * scale);

  int beg = row_ptr[node], end = row_ptr[node + 1];
  float m = -INFINITY, s = 0.f;
  float a[8] = {0.f, 0.f, 0.f, 0.f, 0.f, 0.f, 0.f, 0.f};

  auto update = [&](float score, half8 vh) {
    if (score <= m) {
      float e = __expf(score - m);
      s += e;
#pragma unroll
      for (int j = 0; j < 8; ++j) a[j] = fmaf(e, (float)vh[j], a[j]);
    } else {
      float f = __expf(m - score);  // m=-inf first iter -> f=0
      s = s * f + 1.f;
#pragma unroll
      for (int j = 0; j < 8; ++j) a[j] = fmaf(a[j], f, (float)vh[j]);
      m = score;
    }
  };

  int i = beg;
  for (; i + 2 <= end; i += 2) {
    int s0 = colbuf[i], s1 = colbuf[i + 1];
    const _Float16* b0 = QKV + (size_t)s0 * QKVW;
    const _Float16* b1 = QKV + (size_t)s1 * QKVW;
    half8 k0 = *(const half8*)(b0 + 256 + d);
    half8 k1 = *(const half8*)(b1 + 256 + d);
    half8 v0 = *(const half8*)(b0 + 512 + d);
    half8 v1 = *(const half8*)(b1 + 512 + d);
    float p0 = dot8(qh, k0);
    float p1 = dot8(qh, k1);
    p0 += __shfl_xor(p0, 1);  p1 += __shfl_xor(p1, 1);
    p0 += __shfl_xor(p0, 2);  p1 += __shfl_xor(p1, 2);
    update(p0, v0);
    update(p1, v1);
  }
  if (i < end) {
    int s0 = colbuf[i];
    const _Float16* b0 = QKV + (size_t)s0 * QKVW;
    half8 k0 = *(const half8*)(b0 + 256 + d);
    half8 v0 = *(const half8*)(b0 + 512 + d);
    float p0 = dot8(qh, k0);
    p0 += __shfl_xor(p0, 1);
    p0 += __shfl_xor(p0, 2);
    update(p0, v0);
  }

  half8 o;
  float inv = (s > 0.f) ? (1.f / s) : 0.f;
#pragma unroll
  for (int j = 0; j < 8; ++j) o[j] = (_Float16)(a[j] * inv);
  *(half8*)(out + (size_t)node * HID + d) = o;
}

// ---------- pooling + classifier ----------
__global__ __launch_bounds__(256) void k_pool_partial(const _Float16* __restrict__ h,
                                                      float* __restrict__ partial, int n) {
  int b = blockIdx.x, t = threadIdx.x;
  float s = 0.f;
  for (int r = b; r < n; r += 256) s += (float)h[(size_t)r * HID + t];
  partial[b * HID + t] = s;
}

__global__ __launch_bounds__(256) void k_final(const float* __restrict__ partial,
                                               const float* __restrict__ c1W,
                                               const float* __restrict__ c1b,
                                               const float* __restrict__ c2W,
                                               const float* __restrict__ c2b,
                                               float* __restrict__ out, int n) {
  __shared__ float gl[HID];
  __shared__ float r1[C1DIM];
  int t = threadIdx.x;
  float s = 0.f;
  for (int b = 0; b < 256; b++) s += partial[b * HID + t];
  gl[t] = s / (float)n;
  __syncthreads();
  if (t < C1DIM) {
    float a = c1b[t];
    for (int k = 0; k < HID; k++) a += gl[k] * c1W[k * C1DIM + t];
    r1[t] = fmaxf(a, 0.f);
  }
  __syncthreads();
  if (t < OUTDIM) {
    float a = c2b[t];
    for (int k = 0; k < C1DIM; k++) a += r1[k] * c2W[k * OUTDIM + t];
    out[t] = a;
  }
}

// ---------- host launcher ----------
extern "C" void kernel_launch(void* const* d_in, const int* in_sizes, int n_in,
                              void* d_out, int out_size, void* d_ws, size_t ws_size,
                              hipStream_t stream) {
  const float* x    = (const float*)d_in[0];
  const float* ts   = (const float*)d_in[1];
  const int*   ei   = (const int*)d_in[2];
  const float* freq = (const float*)d_in[4];
  const float* inW  = (const float*)d_in[5];
  const float* inb  = (const float*)d_in[6];
  const float* qW   = (const float*)d_in[7];
  const float* qb   = (const float*)d_in[8];
  const float* kW   = (const float*)d_in[9];
  const float* kb   = (const float*)d_in[10];
  const float* vW   = (const float*)d_in[11];
  const float* vb   = (const float*)d_in[12];
  const float* oW   = (const float*)d_in[13];
  const float* ob   = (const float*)d_in[14];
  const float* c1W  = (const float*)d_in[15];
  const float* c1b  = (const float*)d_in[16];
  const float* c2W  = (const float*)d_in[17];
  const float* c2b  = (const float*)d_in[18];

  int n = in_sizes[1];
  int e = in_sizes[2] / 2;
  const int* src = ei;
  const int* dst = ei + e;

  char* w = (char*)d_ws;
  size_t off = 0;
  auto alloc = [&](size_t bytes) -> char* {
    char* p = w + off;
    off = (off + bytes + 255) & ~(size_t)255;
    return p;
  };
  _Float16* tfh     = (_Float16*)alloc((size_t)n * TD * 2);
  _Float16* xh      = (_Float16*)alloc((size_t)n * 32 * 2);
  _Float16* h       = (_Float16*)alloc((size_t)n * HID * 2);
  _Float16* QKV     = (_Float16*)alloc((size_t)n * QKVW * 2);
  _Float16* ao      = (_Float16*)alloc((size_t)n * HID * 2);
  _Float16* inWt    = (_Float16*)alloc((size_t)32 * HID * 2);
  _Float16* qkvWt   = (_Float16*)alloc((size_t)NL * QKVW * (HID + TD) * 2);
  float*    qkvb    = (float*)alloc((size_t)NL * QKVW * 4);
  _Float16* oWt     = (_Float16*)alloc((size_t)NL * HID * HID * 2);
  int*      deg     = (int*)alloc((size_t)n * 4);
  int*      cursor  = (int*)alloc((size_t)n * 4);
  int*      row_ptr = (int*)alloc((size_t)(n + 1) * 4);
  int*      colbuf  = (int*)alloc((size_t)e * 4);
  float*    partial = (float*)alloc((size_t)256 * HID * 4);
  unsigned* mm      = (unsigned*)alloc(256);

  int b256 = 256;
  hipLaunchKernelGGL(k_init, dim3((n + 255) / 256), dim3(b256), 0, stream, deg, mm, n);
  hipLaunchKernelGGL(k_minmax, dim3(40), dim3(b256), 0, stream, ts, mm, n);
  hipLaunchKernelGGL(k_time_enc, dim3((n * TD + 255) / 256), dim3(b256), 0, stream, ts, freq, mm, tfh, n);
  hipLaunchKernelGGL(k_cvt, dim3((n * 32 + 255) / 256), dim3(b256), 0, stream, x, xh, n * 32);
  hipLaunchKernelGGL(k_wt, dim3((32 * HID + 255) / 256), dim3(b256), 0, stream, inW, inWt, 32, HID, 32 * HID);
  {
    int tq = NL * QKVW * (HID + TD);
    hipLaunchKernelGGL(k_wt_qkv, dim3((tq + 255) / 256), dim3(b256), 0, stream, qW, kW, vW, qkvWt, tq);
    int tb = NL * QKVW;
    hipLaunchKernelGGL(k_fuse_bias, dim3((tb + 255) / 256), dim3(b256), 0, stream, qb, kb, vb, qkvb, tb);
    int tv = NL * HID * HID;
    hipLaunchKernelGGL(k_wt, dim3((tv + 255) / 256), dim3(b256), 0, stream, oW, oWt, HID, HID, tv);
  }
  hipLaunchKernelGGL(k_count, dim3((e + 255) / 256), dim3(b256), 0, stream, dst, deg, e);
  hipLaunchKernelGGL(k_scan, dim3(1), dim3(1024), 0, stream, deg, row_ptr, cursor, n);
  hipLaunchKernelGGL(k_scatter, dim3((e + 255) / 256), dim3(b256), 0, stream, src, dst, row_ptr, cursor, colbuf, e);

  dim3 ggrid_h(HID / 64, (n + 127) / 128);
  dim3 ggrid_qkv(QKVW / 64, (n + 127) / 128);
  hipLaunchKernelGGL(k_gemm_f16, ggrid_h, dim3(b256), 0, stream,
                     xh, 32, xh, 32, inWt, inb, h, n, HID, 32, 0);

  for (int l = 0; l < NL; ++l) {
    const _Float16* qkvWtl = qkvWt + (size_t)l * QKVW * (HID + TD);
    const float*    qkvbl  = qkvb + (size_t)l * QKVW;
    const _Float16* oWtl   = oWt + (size_t)l * HID * HID;
    hipLaunchKernelGGL(k_gemm_f16, ggrid_qkv, dim3(b256), 0, stream,
                       h, HID, tfh, TD, qkvWtl, qkvbl, QKV, n, QKVW, HID + TD, 0);
    hipLaunchKernelGGL(k_attn, dim3((n + 7) / 8), dim3(b256), 0, stream,
                       QKV, row_ptr, colbuf, ao, n);
    hipLaunchKernelGGL(k_gemm_f16, ggrid_h, dim3(b256), 0, stream,
                       ao, HID, ao, HID, oWtl, ob + l * HID, h, n, HID, HID, 1);
  }

  hipLaunchKernelGGL(k_pool_partial, dim3(256), dim3(b256), 0, stream, h, partial, n);
  hipLaunchKernelGGL(k_final, dim3(1), dim3(b256), 0, stream, partial, c1W, c1b, c2W, c2b, (float*)d_out, n);
}